// Round 9
// baseline (697.681 us; speedup 1.0000x reference)
//
#include <hip/hip_runtime.h>
#include <hip/hip_bf16.h>
#include <math.h>

#define D_MODEL 768
#define NH 12
#define HD 64
#define BATCH 2
#define SEQ 4096
#define NROWS (BATCH * SEQ)   // 8192

#define QSCALE 0.18033688011112042f   // 0.125 * log2(e): softmax via exp2

typedef __attribute__((ext_vector_type(8))) short short8;
typedef __attribute__((ext_vector_type(4))) short short4v;
typedef __attribute__((ext_vector_type(4))) float f32x4;
typedef __attribute__((ext_vector_type(16))) float f32x16;

__device__ inline unsigned short f2bf(float f) {
    __hip_bfloat16 h = __float2bfloat16(f);   // RNE
    return *reinterpret_cast<unsigned short*>(&h);
}

// async global->LDS DMA, 16 B per lane; LDS dest is wave-uniform base + lane*16
__device__ __forceinline__ void async_ld16(const unsigned short* g, unsigned short* l) {
    __builtin_amdgcn_global_load_lds(
        (const __attribute__((address_space(1))) void*)g,
        (__attribute__((address_space(3))) void*)l, 16, 0, 0);
}

// ---------------------------------------------------------------------------
// x fp32 -> bf16 (same layout). 8 elems/thread.
// ---------------------------------------------------------------------------
__global__ __launch_bounds__(256) void convert_x_k(
    const float* __restrict__ x, unsigned short* __restrict__ xb)
{
    size_t i = ((size_t)blockIdx.x * 256 + threadIdx.x) * 8;
    float4 a = *(const float4*)(x + i);
    float4 b = *(const float4*)(x + i + 4);
    short8 o;
    o[0] = (short)f2bf(a.x); o[1] = (short)f2bf(a.y);
    o[2] = (short)f2bf(a.z); o[3] = (short)f2bf(a.w);
    o[4] = (short)f2bf(b.x); o[5] = (short)f2bf(b.y);
    o[6] = (short)f2bf(b.z); o[7] = (short)f2bf(b.w);
    *(short8*)(xb + i) = o;
}

// ---------------------------------------------------------------------------
// W fp32 [768][768] -> Wt bf16 [768][768] TRANSPOSED (Wt[n][k] = W[k][n]).
// ---------------------------------------------------------------------------
__global__ __launch_bounds__(256) void convert_wt_k(
    const float* __restrict__ Wq, const float* __restrict__ Wk,
    const float* __restrict__ Wv, const float* __restrict__ Wo,
    unsigned short* __restrict__ wt)
{
    const float* W = (blockIdx.z == 0) ? Wq : (blockIdx.z == 1) ? Wk
                   : (blockIdx.z == 2) ? Wv : Wo;
    unsigned short* dst = wt + (size_t)blockIdx.z * D_MODEL * D_MODEL;
    __shared__ float tile[64][65];
    const int k0 = blockIdx.x * 64, n0 = blockIdx.y * 64;
    const int t = threadIdx.x;
    const int r = t >> 2, seg = t & 3;
    const float* src = W + (size_t)(k0 + r) * D_MODEL + n0 + seg * 16;
    #pragma unroll
    for (int i = 0; i < 4; ++i) {
        float4 v = *(const float4*)(src + i * 4);
        tile[r][seg * 16 + i * 4 + 0] = v.x;
        tile[r][seg * 16 + i * 4 + 1] = v.y;
        tile[r][seg * 16 + i * 4 + 2] = v.z;
        tile[r][seg * 16 + i * 4 + 3] = v.w;
    }
    __syncthreads();
    unsigned short* d = dst + (size_t)(n0 + r) * D_MODEL + k0 + seg * 16;
    short8 o0, o1;
    #pragma unroll
    for (int j = 0; j < 8; ++j) o0[j] = (short)f2bf(tile[seg * 16 + j][r]);
    #pragma unroll
    for (int j = 0; j < 8; ++j) o1[j] = (short)f2bf(tile[seg * 16 + 8 + j][r]);
    *(short8*)(d) = o0;
    *(short8*)(d + 8) = o1;
}

// ---------------------------------------------------------------------------
// QKV projection, bf16 MFMA 16x16x32, M=128 x N=64 tile, BK=64.
// Staging via global_load_lds width=16 (m97 ladder).
// Epilogue: q scaled by 0.125*log2e, v written TRANSPOSED [b,h,d,s].
// ---------------------------------------------------------------------------
__global__ __launch_bounds__(256) void qkv_mfma_k(
    const unsigned short* __restrict__ xb,
    const unsigned short* __restrict__ wt,
    const float* __restrict__ bq, const float* __restrict__ bk,
    const float* __restrict__ bv,
    unsigned short* __restrict__ qb,         // [B,H,S,64] (pre-scaled)
    unsigned short* __restrict__ kb,         // [B,H,S,64]
    unsigned short* __restrict__ vtb)        // [B,H,64,S]
{
    __shared__ unsigned short As[128][64];   // unpadded (DMA-compatible)
    __shared__ unsigned short Bs[64][64];
    const int z = blockIdx.z;
    const unsigned short* Wt = wt + (size_t)z * D_MODEL * D_MODEL;
    const float* bias = (z == 0) ? bq : (z == 1) ? bk : bv;
    const int t = threadIdx.x;
    const int w = t >> 6, lane = t & 63, quad = lane >> 4, col = lane & 15;
    const int r0 = blockIdx.x * 128;
    const int c0 = blockIdx.y * 64;

    f32x4 acc[2][4] = {};

    for (int kk = 0; kk < D_MODEL; kk += 64) {
        __syncthreads();   // prior compute done reading LDS
        #pragma unroll
        for (int j = 0; j < 4; ++j) {
            int c = (w * 4 + j) * 64 + lane;
            async_ld16(xb + (size_t)(r0 + (c >> 3)) * D_MODEL + kk + (c & 7) * 8,
                       &As[0][0] + (size_t)c * 8);
        }
        #pragma unroll
        for (int j = 0; j < 2; ++j) {
            int c = (w * 2 + j) * 64 + lane;
            async_ld16(Wt + (size_t)(c0 + (c >> 3)) * D_MODEL + kk + (c & 7) * 8,
                       &Bs[0][0] + (size_t)c * 8);
        }
        __syncthreads();   // DMA drained by pre-barrier vmcnt(0)
        #pragma unroll
        for (int ks = 0; ks < 2; ++ks) {
            short8 af[2], bf[4];
            af[0] = *(const short8*)&As[w * 32 + col][ks * 32 + quad * 8];
            af[1] = *(const short8*)&As[w * 32 + 16 + col][ks * 32 + quad * 8];
            #pragma unroll
            for (int nt = 0; nt < 4; ++nt)
                bf[nt] = *(const short8*)&Bs[nt * 16 + col][ks * 32 + quad * 8];
            #pragma unroll
            for (int mt = 0; mt < 2; ++mt)
                #pragma unroll
                for (int nt = 0; nt < 4; ++nt)
                    acc[mt][nt] = __builtin_amdgcn_mfma_f32_16x16x32_bf16(
                        af[mt], bf[nt], acc[mt][nt], 0, 0, 0);
        }
    }

    const int h = blockIdx.y;
    #pragma unroll
    for (int nt = 0; nt < 4; ++nt) {
        const float bv_ = bias[c0 + nt * 16 + col];
        const int hd = nt * 16 + col;
        #pragma unroll
        for (int mt = 0; mt < 2; ++mt) {
            #pragma unroll
            for (int reg = 0; reg < 4; ++reg) {
                int r = r0 + w * 32 + mt * 16 + quad * 4 + reg;
                int b = r >> 12, s = r & (SEQ - 1);
                float val = acc[mt][nt][reg] + bv_;
                size_t bh = (size_t)(b * NH + h);
                if (z == 0)
                    qb[(bh * SEQ + s) * HD + hd] = f2bf(val * QSCALE);
                else if (z == 1)
                    kb[(bh * SEQ + s) * HD + hd] = f2bf(val);
                else
                    vtb[(bh * HD + hd) * SEQ + s] = f2bf(val);
            }
        }
    }
}

// ---------------------------------------------------------------------------
// Output projection: out = ab @ Wo + bo, fp32 out. Same DMA staging.
// ---------------------------------------------------------------------------
__global__ __launch_bounds__(256) void out_mfma_k(
    const unsigned short* __restrict__ ab,
    const unsigned short* __restrict__ wot,
    const float* __restrict__ bo,
    float* __restrict__ out)
{
    __shared__ unsigned short As[128][64];
    __shared__ unsigned short Bs[64][64];
    const int t = threadIdx.x;
    const int w = t >> 6, lane = t & 63, quad = lane >> 4, col = lane & 15;
    const int r0 = blockIdx.x * 128;
    const int c0 = blockIdx.y * 64;

    f32x4 acc[2][4] = {};

    for (int kk = 0; kk < D_MODEL; kk += 64) {
        __syncthreads();
        #pragma unroll
        for (int j = 0; j < 4; ++j) {
            int c = (w * 4 + j) * 64 + lane;
            async_ld16(ab + (size_t)(r0 + (c >> 3)) * D_MODEL + kk + (c & 7) * 8,
                       &As[0][0] + (size_t)c * 8);
        }
        #pragma unroll
        for (int j = 0; j < 2; ++j) {
            int c = (w * 2 + j) * 64 + lane;
            async_ld16(wot + (size_t)(c0 + (c >> 3)) * D_MODEL + kk + (c & 7) * 8,
                       &Bs[0][0] + (size_t)c * 8);
        }
        __syncthreads();
        #pragma unroll
        for (int ks = 0; ks < 2; ++ks) {
            short8 af[2], bf[4];
            af[0] = *(const short8*)&As[w * 32 + col][ks * 32 + quad * 8];
            af[1] = *(const short8*)&As[w * 32 + 16 + col][ks * 32 + quad * 8];
            #pragma unroll
            for (int nt = 0; nt < 4; ++nt)
                bf[nt] = *(const short8*)&Bs[nt * 16 + col][ks * 32 + quad * 8];
            #pragma unroll
            for (int mt = 0; mt < 2; ++mt)
                #pragma unroll
                for (int nt = 0; nt < 4; ++nt)
                    acc[mt][nt] = __builtin_amdgcn_mfma_f32_16x16x32_bf16(
                        af[mt], bf[nt], acc[mt][nt], 0, 0, 0);
        }
    }

    #pragma unroll
    for (int nt = 0; nt < 4; ++nt) {
        const float bv_ = bo[c0 + nt * 16 + col];
        #pragma unroll
        for (int mt = 0; mt < 2; ++mt) {
            #pragma unroll
            for (int reg = 0; reg < 4; ++reg) {
                int r = r0 + w * 32 + mt * 16 + quad * 4 + reg;
                out[(size_t)r * D_MODEL + c0 + nt * 16 + col] = acc[mt][nt][reg] + bv_;
            }
        }
    }
}

// ---------------------------------------------------------------------------
// Flash attention, bf16 MFMA 32x32x16, transposed scores, fixed-max softmax.
// NEW partition: block = (b, h, 128-q); waves {0,1} own q 0-63, waves {2,3}
// own q 64-127; within a pair each wave takes HALF the 64-k tile. This halves
// per-wave K/V LDS re-reads (the measured bottleneck); O/l are k-partial and
// pair-summed once after the loop via an LDS overlay. P stays wave-private.
// Strides: Ks/Vts 66 shorts (33 dw), Ps 34 shorts (17 dw) -> 0 conflicts.
// ---------------------------------------------------------------------------
__global__ __launch_bounds__(256) void flash_mfma_k(
    const unsigned short* __restrict__ qb,   // [B*NH][SEQ][64], pre-scaled
    const unsigned short* __restrict__ kb,   // [B*NH][SEQ][64]
    const unsigned short* __restrict__ vtb,  // [B*NH][64][SEQ]
    unsigned short* __restrict__ ab)         // [B][SEQ][768] bf16
{
    __shared__ __align__(16) unsigned char smem[34304];
    unsigned short (*Ks)[66]  = (unsigned short(*)[66])smem;            // 64 rows
    unsigned short (*Vts)[66] = (unsigned short(*)[66])(smem + 8448);   // 64 rows
    unsigned short (*Ps)[34]  = (unsigned short(*)[34])(smem + 16896);  // 256 rows
    float* Red = (float*)smem;  // post-loop overlay: [2][64 lanes][66 floats]

    const int t = threadIdx.x;
    const int w = t >> 6, lane = t & 63;
    const int l31 = lane & 31, hi = lane >> 5;
    const int qgrp = w >> 1;          // 0: q 0-63, 1: q 64-127
    const int khalf = w & 1;          // 0: k 0-31, 1: k 32-63 of each tile
    const int q0 = blockIdx.x * 128;
    const int h = blockIdx.y, b = blockIdx.z;
    const size_t bh = (size_t)b * NH + h;
    const unsigned short* qg = qb + bh * SEQ * HD;
    const unsigned short* kg = kb + bh * SEQ * HD;
    const unsigned short* vg = vtb + bh * HD * SEQ;

    // persistent Q B-frags: q(n) = q0 + qgrp*64 + qt*32 + l31, d = ks2*16+hi*8+j
    short8 qf[2][4];
    #pragma unroll
    for (int qt = 0; qt < 2; ++qt) {
        const unsigned short* src =
            qg + (size_t)(q0 + qgrp * 64 + qt * 32 + l31) * HD + hi * 8;
        #pragma unroll
        for (int ks2 = 0; ks2 < 4; ++ks2)
            qf[qt][ks2] = *(const short8*)(src + ks2 * 16);
    }

    f32x16 oacc[2][2] = {};   // [dt][qt]; d = dt*32+(reg&3)+8*(reg>>2)+4*hi, q = l31
    float lsum[2] = {0.f, 0.f};
    const int srow = lane, sseg = w;

    for (int kt = 0; kt < SEQ; kt += 64) {
        // prefetch K / V^T tiles into registers, then stage to LDS
        const unsigned short* kp = kg + (size_t)(kt + srow) * HD + sseg * 16;
        short8 kr0 = *(const short8*)(kp);
        short8 kr1 = *(const short8*)(kp + 8);
        const unsigned short* vp = vg + (size_t)srow * SEQ + kt + sseg * 16;
        short8 vr0 = *(const short8*)(vp);
        short8 vr1 = *(const short8*)(vp + 8);
        __syncthreads();
        *(short8*)&Ks[srow][sseg * 16]      = kr0;
        *(short8*)&Ks[srow][sseg * 16 + 8]  = kr1;
        *(short8*)&Vts[srow][sseg * 16]     = vr0;
        *(short8*)&Vts[srow][sseg * 16 + 8] = vr1;
        __syncthreads();

        // S^T = K Q^T on this wave's k-half; softmax + P^T pack, per qt
        {
            short8 kf[4];
            #pragma unroll
            for (int ks2 = 0; ks2 < 4; ++ks2)
                kf[ks2] = *(const short8*)&Ks[khalf * 32 + l31][ks2 * 16 + hi * 8];
            #pragma unroll
            for (int qt = 0; qt < 2; ++qt) {
                f32x16 s = {};
                #pragma unroll
                for (int ks2 = 0; ks2 < 4; ++ks2)
                    s = __builtin_amdgcn_mfma_f32_32x32x16_bf16(
                        kf[ks2], qf[qt][ks2], s, 0, 0, 0);
                #pragma unroll
                for (int rq = 0; rq < 4; ++rq) {
                    float p0 = __builtin_amdgcn_exp2f(s[rq * 4 + 0]);
                    float p1 = __builtin_amdgcn_exp2f(s[rq * 4 + 1]);
                    float p2 = __builtin_amdgcn_exp2f(s[rq * 4 + 2]);
                    float p3 = __builtin_amdgcn_exp2f(s[rq * 4 + 3]);
                    lsum[qt] += (p0 + p1) + (p2 + p3);
                    short4v pk;
                    pk[0] = (short)f2bf(p0);
                    pk[1] = (short)f2bf(p1);
                    pk[2] = (short)f2bf(p2);
                    pk[3] = (short)f2bf(p3);
                    // k-local = rq*8 + hi*4 + i (C row pattern), row q = l31
                    *(short4v*)&Ps[w * 64 + qt * 32 + l31][rq * 8 + hi * 4] = pk;
                }
            }
        }

        // PV partial over this k-half: O^T += V^T P  (wave-private Ps)
        #pragma unroll
        for (int ks = 0; ks < 2; ++ks) {
            short8 pf[2];
            #pragma unroll
            for (int qt = 0; qt < 2; ++qt)
                pf[qt] = *(const short8*)&Ps[w * 64 + qt * 32 + l31][ks * 16 + hi * 8];
            #pragma unroll
            for (int dt = 0; dt < 2; ++dt) {
                short8 vf = *(const short8*)
                    &Vts[dt * 32 + l31][khalf * 32 + ks * 16 + hi * 8];
                #pragma unroll
                for (int qt = 0; qt < 2; ++qt)
                    oacc[dt][qt] = __builtin_amdgcn_mfma_f32_32x32x16_bf16(
                        vf, pf[qt], oacc[dt][qt], 0, 0, 0);
            }
        }
    }

    // cross-hi l reduction (same q = l31 in both hi halves)
    lsum[0] += __shfl_xor(lsum[0], 32);
    lsum[1] += __shfl_xor(lsum[1], 32);

    // pair reduction over k-halves via LDS overlay, then normalize + store
    __syncthreads();   // all loop reads of Ks/Vts/Ps done before overwrite
    if (khalf == 1) {
        float* R = Red + qgrp * (64 * 66) + lane * 66;
        #pragma unroll
        for (int dt = 0; dt < 2; ++dt)
            #pragma unroll
            for (int qt = 0; qt < 2; ++qt)
                #pragma unroll
                for (int reg = 0; reg < 16; ++reg)
                    R[dt * 32 + qt * 16 + reg] = oacc[dt][qt][reg];
        R[64] = lsum[0];
        R[65] = lsum[1];
    }
    __syncthreads();
    if (khalf == 0) {
        const float* R = Red + qgrp * (64 * 66) + lane * 66;
        #pragma unroll
        for (int dt = 0; dt < 2; ++dt)
            #pragma unroll
            for (int qt = 0; qt < 2; ++qt)
                #pragma unroll
                for (int reg = 0; reg < 16; ++reg)
                    oacc[dt][qt][reg] += R[dt * 32 + qt * 16 + reg];
        float ltot[2] = {lsum[0] + R[64], lsum[1] + R[65]};
        #pragma unroll
        for (int qt = 0; qt < 2; ++qt) {
            float inv = 1.0f / ltot[qt];
            int s = q0 + qgrp * 64 + qt * 32 + l31;
            unsigned short* dst = ab + ((size_t)b * SEQ + s) * D_MODEL + h * HD;
            #pragma unroll
            for (int dt = 0; dt < 2; ++dt) {
                #pragma unroll
                for (int rq = 0; rq < 4; ++rq) {
                    short4v o4;
                    o4[0] = (short)f2bf(oacc[dt][qt][rq * 4 + 0] * inv);
                    o4[1] = (short)f2bf(oacc[dt][qt][rq * 4 + 1] * inv);
                    o4[2] = (short)f2bf(oacc[dt][qt][rq * 4 + 2] * inv);
                    o4[3] = (short)f2bf(oacc[dt][qt][rq * 4 + 3] * inv);
                    *(short4v*)(dst + dt * 32 + rq * 8 + hi * 4) = o4;
                }
            }
        }
    }
}

extern "C" void kernel_launch(void* const* d_in, const int* in_sizes, int n_in,
                              void* d_out, int out_size, void* d_ws, size_t ws_size,
                              hipStream_t stream)
{
    const float* x  = (const float*)d_in[0];
    const float* Wq = (const float*)d_in[1];
    const float* bq = (const float*)d_in[2];
    const float* Wk = (const float*)d_in[3];
    const float* bk = (const float*)d_in[4];
    const float* Wv = (const float*)d_in[5];
    const float* bv = (const float*)d_in[6];
    const float* Wo = (const float*)d_in[7];
    const float* bo = (const float*)d_in[8];
    float* out = (float*)d_out;

    const size_t n_x  = (size_t)NROWS * D_MODEL;
    const size_t n_w  = (size_t)D_MODEL * D_MODEL;
    unsigned short* xb  = (unsigned short*)d_ws;
    unsigned short* wt  = xb + n_x;
    unsigned short* qb  = wt + 4 * n_w;
    unsigned short* kb  = qb + n_x;
    unsigned short* vtb = kb + n_x;
    unsigned short* ab  = vtb + n_x;
    const size_t need = ((size_t)4 * n_x + 4 * n_w + n_x) * sizeof(unsigned short);
    if (ws_size < need) return;

    convert_x_k<<<dim3((int)(n_x / 2048)), 256, 0, stream>>>(x, xb);
    convert_wt_k<<<dim3(12, 12, 4), 256, 0, stream>>>(Wq, Wk, Wv, Wo, wt);
    qkv_mfma_k<<<dim3(NROWS / 128, D_MODEL / 64, 3), 256, 0, stream>>>(
        xb, wt, bq, bk, bv, qb, kb, vtb);
    flash_mfma_k<<<dim3(SEQ / 128, NH, BATCH), 256, 0, stream>>>(qb, kb, vtb, ab);
    out_mfma_k<<<dim3(NROWS / 128, D_MODEL / 64), 256, 0, stream>>>(
        ab, wt + 3 * n_w, bo, out);
}